// Round 19
// baseline (181.001 us; speedup 1.0000x reference)
//
#include <hip/hip_runtime.h>

#define HID   2048
#define KD    2048
#define GQ    4
#define HPGQ  4
#define DH    128
#define SEQ   2048
#define NBATCH 2
#define NTOK  (NBATCH * SEQ)   // 4096
#define NQKV  3072

typedef unsigned short u16;
typedef unsigned int   u32;
using bf16x8 = __attribute__((ext_vector_type(8))) __bf16;
using bf16x2 = __attribute__((ext_vector_type(2))) __bf16;
using f32x4  = __attribute__((ext_vector_type(4))) float;
using u32x4  = __attribute__((ext_vector_type(4))) u32;

#if __has_builtin(__builtin_amdgcn_exp2f)
#define FEXP2(x) __builtin_amdgcn_exp2f(x)
#else
#define FEXP2(x) exp2f(x)
#endif

// 1/sqrt(128) * log2(e): folded into Q projection so scores are in log2 domain
#define QSCALE 0.12751744f

__device__ __forceinline__ u16 f2bf(float f) {
  union { float f; u32 u; } v; v.f = f;
  u32 u = v.u + 0x7fffu + ((v.u >> 16) & 1u);
  return (u16)(u >> 16);
}

__device__ __forceinline__ u32 pk2(float a, float b) {
  bf16x2 t;
  t[0] = (__bf16)a;
  t[1] = (__bf16)b;
  return __builtin_bit_cast(u32, t);
}

__device__ __forceinline__ void gl16(const void* g, void* l) {
  __builtin_amdgcn_global_load_lds((const __attribute__((address_space(1))) u32*)g,
                                   (__attribute__((address_space(3))) u32*)l, 16, 0, 0);
}

// staging-side swizzle (only used OUTSIDE hot loops, for lane-invariant offsets)
__device__ __forceinline__ int swz(int r, int c) {
  return (c & ~7) | ((c ^ r ^ (r >> 3)) & 7);
}

// ---------------- fused prep: fp32->bf16 convert of x + all weight transposes ----
__global__ __launch_bounds__(256) void k_prep(
    const float* __restrict__ x, u16* __restrict__ x_bf,
    const float* __restrict__ Wq, const float* __restrict__ Wk,
    const float* __restrict__ Wv, const float* __restrict__ Wo,
    u16* __restrict__ qkvT, u16* __restrict__ WoT) {
  __shared__ float tile[32][33];
  const int bid = blockIdx.x;
  if (bid < 8192) {
    const int i = bid * 256 + threadIdx.x;
    const float4 v = ((const float4*)x)[i];
    ushort4 o;
    o.x = f2bf(v.x); o.y = f2bf(v.y); o.z = f2bf(v.z); o.w = f2bf(v.w);
    ((ushort4*)x_bf)[i] = o;
    return;
  }
  int idx = bid - 8192;
  const float* W; u16* WT; int N, rowoff, bx, by;
  if (idx < 4096)      {             W = Wq; WT = qkvT; N = 2048; rowoff = 0;    bx = idx & 63; by = idx >> 6; }
  else if (idx < 5120) { idx -= 4096; W = Wk; WT = qkvT; N = 512;  rowoff = 2048; bx = idx & 15; by = idx >> 4; }
  else if (idx < 6144) { idx -= 5120; W = Wv; WT = qkvT; N = 512;  rowoff = 2560; bx = idx & 15; by = idx >> 4; }
  else                 { idx -= 6144; W = Wo; WT = WoT;  N = 2048; rowoff = 0;    bx = idx & 63; by = idx >> 6; }
  const int tx = threadIdx.x & 31, ty = threadIdx.x >> 5;
  const int k0 = by * 32, n0 = bx * 32;
#pragma unroll
  for (int i = 0; i < 4; ++i)
    tile[ty + 8 * i][tx] = W[(size_t)(k0 + ty + 8 * i) * N + (n0 + tx)];
  __syncthreads();
#pragma unroll
  for (int i = 0; i < 4; ++i)
    WT[(size_t)(rowoff + n0 + ty + 8 * i) * KD + (k0 + tx)] = f2bf(tile[tx][ty + 8 * i]);
}

// ================= 256x192 8-wave pipelined GEMM (QKV) — round-15 version ========
#define BUFB 57344

#define STG128(OP, ROWB, KTB, LBYTE)                                               \
  { _Pragma("unroll") for (int i = 0; i < 2; ++i)                                  \
      gl16((OP) + (size_t)(ROWB) * KD + (KTB) + stOffE[i],                         \
           (u16*)((char*)S + (LBYTE)) + (i * 512 + t) * 8); }
#define STG64(OP, ROWB, KTB, LBYTE)                                                \
  gl16((OP) + (size_t)(ROWB) * KD + (KTB) + stOffE[0],                             \
       (u16*)((char*)S + (LBYTE)) + t * 8);

#define STAGE_B(D, KTB)                                                            \
  STG128(Bt, n0b,       (KTB), (D) * BUFB + 32768);                                \
  STG64 (Bt, n0b + 128, (KTB), (D) * BUFB + 49152);
#define STAGE_A(D, KTB)                                                            \
  STG128(A,  m0,        (KTB), (D) * BUFB + 0);                                    \
  STG128(A,  m0 + 128,  (KTB), (D) * BUFB + 16384);

#define RDA(D, M, KC) (*(const bf16x8*)((const char*)S + (D) * BUFB + (M) * 2048 + (aQ ^ ((KC) << 6))))
#define RDB(D, NT, KC) (*(const bf16x8*)((const char*)S + (D) * BUFB + (NT) * 2048 + (bQ ^ ((KC) << 6))))

#define MFMA8(MB, NT)                                                              \
  _Pragma("unroll") for (int m = 0; m < 4; ++m)                                    \
    _Pragma("unroll") for (int kc = 0; kc < 2; ++kc)                               \
      acc[(MB) + m][NT] = __builtin_amdgcn_mfma_f32_16x16x32_bf16(                 \
          afr[m][kc], bfr[NT][kc], acc[(MB) + m][NT], 0, 0, 0);

#define ITERQ(D, KTN, PRE)                                                         \
  do {                                                                             \
    _Pragma("unroll") for (int m = 0; m < 4; ++m)                                  \
      _Pragma("unroll") for (int kc = 0; kc < 2; ++kc)                             \
        afr[m][kc] = RDA(D, m, kc);                                                \
    _Pragma("unroll") for (int nt = 0; nt < 3; ++nt)                               \
      _Pragma("unroll") for (int kc = 0; kc < 2; ++kc)                             \
        bfr[nt][kc] = RDB(D, nt, kc);                                              \
    __builtin_amdgcn_s_setprio(1);                                                 \
    MFMA8(0, 0) MFMA8(0, 1) MFMA8(0, 2)                                            \
    __builtin_amdgcn_s_setprio(0);                                                 \
    _Pragma("unroll") for (int m = 0; m < 4; ++m)                                  \
      _Pragma("unroll") for (int kc = 0; kc < 2; ++kc)                             \
        afr[m][kc] = RDA(D, 4 + m, kc);                                            \
    asm volatile("s_waitcnt lgkmcnt(0)" ::: "memory");                             \
    __builtin_amdgcn_s_barrier();                                                  \
    if (PRE) {                                                                     \
      STAGE_B(D, KTN);                                                             \
      STAGE_A(D, KTN);                                                             \
      asm volatile("s_waitcnt vmcnt(7)" ::: "memory");                             \
    } else {                                                                       \
      asm volatile("s_waitcnt vmcnt(0)" ::: "memory");                             \
    }                                                                              \
    __builtin_amdgcn_s_barrier();                                                  \
    __builtin_amdgcn_s_setprio(1);                                                 \
    MFMA8(4, 0) MFMA8(4, 1) MFMA8(4, 2)                                            \
    __builtin_amdgcn_s_setprio(0);                                                 \
  } while (0)

__global__ __launch_bounds__(512, 1) void k_gemm_qkv(
    const u16* __restrict__ A, const u16* __restrict__ Bt,
    u16* __restrict__ qkv, u16* __restrict__ vT,
    const float* __restrict__ bq, const float* __restrict__ bk,
    const float* __restrict__ bv) {
  __shared__ u16 S[BUFB];                     // 112 KiB
  const int t = threadIdx.x, l = t & 63, w = t >> 6;
  const int lr = l & 15, lk = l >> 4;
  const int wm = w >> 2, wn = w & 3;
  const int m0 = blockIdx.y * 256, n0b = blockIdx.x * 192;

  int stOffE[2];
#pragma unroll
  for (int i = 0; i < 2; ++i) {
    const int e = i * 512 + t;
    const int r = e >> 3;
    stOffE[i] = r * KD + ((e & 7) ^ (r & 7)) * 8;
  }
  const int qb = lr * 128 + (((lr >> 2) & 1) << 6) + ((lk ^ (lr & 3)) << 4);
  const int aQ = wm * 16384 + qb;
  const int bQ = 32768 + wn * 6144 + qb;

  f32x4 acc[8][3] = {};
  bf16x8 afr[4][2], bfr[3][2];

  STAGE_A(0, 0);  STAGE_B(0, 0);
  STAGE_A(1, 64); STAGE_B(1, 64);
  asm volatile("s_waitcnt vmcnt(7)" ::: "memory");
  __builtin_amdgcn_s_barrier();

  for (int j = 0; j < 30; j += 2) {
    ITERQ(0, (j + 2) * 64, true);
    ITERQ(1, (j + 3) * 64, true);
  }
  ITERQ(0, 0, false);
  ITERQ(1, 0, false);

  const int gmB = m0 + wm * 128, gnB = n0b + wn * 48;
#pragma unroll
  for (int m = 0; m < 8; ++m) {
    const int row0 = gmB + m * 16 + lk * 4;
#pragma unroll
    for (int nt = 0; nt < 3; ++nt) {
      const int col = gnB + nt * 16 + lr;
      float bias, qs = 1.0f;
      if (col < HID) { bias = bq[col]; qs = QSCALE; }
      else if (col < HID + 512) bias = bk[col - HID];
      else bias = bv[col - HID - 512];
      if (col < HID + 512) {
#pragma unroll
        for (int r = 0; r < 4; ++r)
          qkv[(size_t)(row0 + r) * NQKV + col] = f2bf((acc[m][nt][r] + bias) * qs);
      } else {
        const int gg = (col - 2560) >> 7, d = (col - 2560) & 127;
        const int b = row0 >> 11, s0 = row0 & 2047;
        ushort4 pk;
        pk.x = f2bf(acc[m][nt][0] + bias);
        pk.y = f2bf(acc[m][nt][1] + bias);
        pk.z = f2bf(acc[m][nt][2] + bias);
        pk.w = f2bf(acc[m][nt][3] + bias);
        *(ushort4*)(vT + ((size_t)(b * GQ + gg) * DH + d) * SEQ + s0) = pk;
      }
    }
  }
}

// ================= 256x128 8-wave pipelined GEMM (O projection) — round-15 ======
#define OBUFB 49152

#define OSTAGE_B(D, KTB)                                                           \
  STG128(Bt, n0b, (KTB), (D) * OBUFB + 32768);
#define OSTAGE_A(D, KTB)                                                           \
  STG128(A,  m0,       (KTB), (D) * OBUFB + 0);                                    \
  STG128(A,  m0 + 128, (KTB), (D) * OBUFB + 16384);

#define ORDA(D, M, KC) (*(const bf16x8*)((const char*)S + (D) * OBUFB + (M) * 2048 + (aQ ^ ((KC) << 6))))
#define ORDB(D, NT, KC) (*(const bf16x8*)((const char*)S + (D) * OBUFB + (NT) * 2048 + (bQ ^ ((KC) << 6))))

#define OMFMA8(MB, NT)                                                             \
  _Pragma("unroll") for (int m = 0; m < 4; ++m)                                    \
    _Pragma("unroll") for (int kc = 0; kc < 2; ++kc)                               \
      acc[(MB) + m][NT] = __builtin_amdgcn_mfma_f32_16x16x32_bf16(                 \
          afr[m][kc], bfr[NT][kc], acc[(MB) + m][NT], 0, 0, 0);

#define ITERO(D, KTN, PRE)                                                         \
  do {                                                                             \
    _Pragma("unroll") for (int m = 0; m < 4; ++m)                                  \
      _Pragma("unroll") for (int kc = 0; kc < 2; ++kc)                             \
        afr[m][kc] = ORDA(D, m, kc);                                               \
    _Pragma("unroll") for (int nt = 0; nt < 2; ++nt)                               \
      _Pragma("unroll") for (int kc = 0; kc < 2; ++kc)                             \
        bfr[nt][kc] = ORDB(D, nt, kc);                                             \
    __builtin_amdgcn_s_setprio(1);                                                 \
    OMFMA8(0, 0) OMFMA8(0, 1)                                                      \
    __builtin_amdgcn_s_setprio(0);                                                 \
    _Pragma("unroll") for (int m = 0; m < 4; ++m)                                  \
      _Pragma("unroll") for (int kc = 0; kc < 2; ++kc)                             \
        afr[m][kc] = ORDA(D, 4 + m, kc);                                           \
    asm volatile("s_waitcnt lgkmcnt(0)" ::: "memory");                             \
    __builtin_amdgcn_s_barrier();                                                  \
    if (PRE) {                                                                     \
      OSTAGE_B(D, KTN);                                                            \
      OSTAGE_A(D, KTN);                                                            \
      asm volatile("s_waitcnt vmcnt(6)" ::: "memory");                             \
    } else {                                                                       \
      asm volatile("s_waitcnt vmcnt(0)" ::: "memory");                             \
    }                                                                              \
    __builtin_amdgcn_s_barrier();                                                  \
    __builtin_amdgcn_s_setprio(1);                                                 \
    OMFMA8(4, 0) OMFMA8(4, 1)                                                      \
    __builtin_amdgcn_s_setprio(0);                                                 \
  } while (0)

__global__ __launch_bounds__(512, 1) void k_gemm_o(
    const u16* __restrict__ A, const u16* __restrict__ Bt,
    const float* __restrict__ bo, float* __restrict__ C) {
  __shared__ u16 S[OBUFB];                    // 96 KiB
  const int t = threadIdx.x, l = t & 63, w = t >> 6;
  const int lr = l & 15, lk = l >> 4;
  const int wm = w >> 2, wn = w & 3;
  const int m0 = blockIdx.y * 256, n0b = blockIdx.x * 128;

  int stOffE[2];
#pragma unroll
  for (int i = 0; i < 2; ++i) {
    const int e = i * 512 + t;
    const int r = e >> 3;
    stOffE[i] = r * KD + ((e & 7) ^ (r & 7)) * 8;
  }
  const int qb = lr * 128 + (((lr >> 2) & 1) << 6) + ((lk ^ (lr & 3)) << 4);
  const int aQ = wm * 16384 + qb;
  const int bQ = 32768 + wn * 4096 + qb;

  f32x4 acc[8][2] = {};
  bf16x8 afr[4][2], bfr[2][2];

  OSTAGE_A(0, 0);  OSTAGE_B(0, 0);
  OSTAGE_A(1, 64); OSTAGE_B(1, 64);
  asm volatile("s_waitcnt vmcnt(6)" ::: "memory");
  __builtin_amdgcn_s_barrier();

  for (int j = 0; j < 30; j += 2) {
    ITERO(0, (j + 2) * 64, true);
    ITERO(1, (j + 3) * 64, true);
  }
  ITERO(0, 0, false);
  ITERO(1, 0, false);

  const int gmB = m0 + wm * 128, gnB = n0b + wn * 32;
#pragma unroll
  for (int m = 0; m < 8; ++m) {
    const int row0 = gmB + m * 16 + lk * 4;
#pragma unroll
    for (int nt = 0; nt < 2; ++nt) {
      const int col = gnB + nt * 16 + lr;
      const float bias = bo[col];
#pragma unroll
      for (int r = 0; r < 4; ++r)
        C[(size_t)(row0 + r) * HID + col] = acc[m][nt][r] + bias;
    }
  }
}

// ================= Flash attention (round-12 proven structure; mk-outer QK) ======
// QBLK=128, KVBLK=32, dbuf K/V (32 KiB), 2 barriers/iter (proven race-free).
// QK^T computed mk-outer: sc[.][0] finishes 8 MFMAs early and its 8 FEXP2s are
// issued immediately — register-independent of the mk=1 MFMA block, so the
// scheduler hides ~half the exp/pack VALU chain under the matrix pipe. Identical
// memory ops, identical per-register accumulation order -> bit-identical result.
#define ATTN_ITER(KS, VS, KN, VN, TTV, PRE)                                        \
  do {                                                                             \
    if (PRE) {                                                                     \
      const int t0n = ((start + (TTV) + 1) & (NT - 1)) * 32;                       \
      const u16* kbT = kbase + (size_t)t0n * NQKV;                                 \
      const u16* vbT = vbase + t0n;                                                \
      _Pragma("unroll")                                                            \
      for (int i = 0; i < 2; ++i) {                                                \
        gl16(kbT + kOffE[i], (KN) + (i * 256 + t) * 8);                            \
        gl16(vbT + vOffE[i], (VN) + (i * 256 + t) * 8);                            \
      }                                                                            \
      asm volatile("s_waitcnt vmcnt(4)" ::: "memory");                             \
    } else {                                                                       \
      asm volatile("s_waitcnt vmcnt(0)" ::: "memory");                             \
    }                                                                              \
    __builtin_amdgcn_s_barrier();                                                  \
    f32x4 sc[2][2] = {};                                                           \
    float ex0[2][4];                                                               \
    __builtin_amdgcn_s_setprio(1);                                                 \
    /* mk = 0 slice: 8 MFMAs -> sc[.][0] complete */                               \
    _Pragma("unroll")                                                              \
    for (int kk = 0; kk < 4; ++kk) {                                               \
      const int LIT0 = ((kk >> 1) << 7) ^ ((kk & 1) << 6);                         \
      const bf16x8 kf0 = *(const bf16x8*)((const char*)(KS) + (kQ0 ^ LIT0));       \
      _Pragma("unroll")                                                            \
      for (int nq = 0; nq < 2; ++nq)                                               \
        sc[nq][0] = __builtin_amdgcn_mfma_f32_16x16x32_bf16(kf0, qf[nq][kk], sc[nq][0], 0, 0, 0); \
    }                                                                              \
    __builtin_amdgcn_s_setprio(0);                                                 \
    /* exp of mk=0 slice (independent of mk=1 MFMAs below) */                      \
    _Pragma("unroll")                                                              \
    for (int nq = 0; nq < 2; ++nq)                                                 \
      _Pragma("unroll")                                                            \
      for (int r = 0; r < 4; ++r) ex0[nq][r] = FEXP2(sc[nq][0][r]);                \
    __builtin_amdgcn_s_setprio(1);                                                 \
    /* mk = 1 slice: 8 MFMAs -> sc[.][1] */                                        \
    _Pragma("unroll")                                                              \
    for (int kk = 0; kk < 4; ++kk) {                                               \
      const int LIT1 = (1 << 12) ^ ((kk >> 1) << 7) ^ ((kk & 1) << 6) ^ (1 << 5);  \
      const bf16x8 kf1 = *(const bf16x8*)((const char*)(KS) + (kQ0 ^ LIT1));       \
      _Pragma("unroll")                                                            \
      for (int nq = 0; nq < 2; ++nq)                                               \
        sc[nq][1] = __builtin_amdgcn_mfma_f32_16x16x32_bf16(kf1, qf[nq][kk], sc[nq][1], 0, 0, 0); \
    }                                                                              \
    __builtin_amdgcn_s_setprio(0);                                                 \
    bf16x8 pa[2];                                                                  \
    _Pragma("unroll")                                                              \
    for (int nq = 0; nq < 2; ++nq) {                                               \
      u32 w0 = pk2(ex0[nq][0], ex0[nq][1]);                                        \
      u32 w1 = pk2(ex0[nq][2], ex0[nq][3]);                                        \
      u32 w2 = pk2(FEXP2(sc[nq][1][0]), FEXP2(sc[nq][1][1]));                      \
      u32 w3 = pk2(FEXP2(sc[nq][1][2]), FEXP2(sc[nq][1][3]));                      \
      asm("v_permlane32_swap_b32 %0, %1" : "+v"(w0), "+v"(w2));                    \
      asm("v_permlane32_swap_b32 %0, %1" : "+v"(w1), "+v"(w3));                    \
      asm("v_permlane16_swap_b32 %0, %1" : "+v"(w0), "+v"(w2));                    \
      asm("v_permlane16_swap_b32 %0, %1" : "+v"(w1), "+v"(w3));                    \
      u32x4 u = {w0, w1, w2, w3};                                                  \
      pa[nq] = __builtin_bit_cast(bf16x8, u);                                      \
    }                                                                              \
    __builtin_amdgcn_s_setprio(1);                                                 \
    _Pragma("unroll")                                                              \
    for (int nq = 0; nq < 2; ++nq)                                                 \
      acc_s[nq] = __builtin_amdgcn_mfma_f32_16x16x32_bf16(pa[nq], vones, acc_s[nq], 0, 0, 0); \
    _Pragma("unroll")                                                              \
    for (int nd = 0; nd < 8; ++nd) {                                               \
      const bf16x8 vf = *(const bf16x8*)((const char*)(VS) + vQ0 + nd * 1024);     \
      _Pragma("unroll")                                                            \
      for (int nq = 0; nq < 2; ++nq)                                               \
        acc_o[nq][nd] = __builtin_amdgcn_mfma_f32_16x16x32_bf16(pa[nq], vf, acc_o[nq][nd], 0, 0, 0); \
    }                                                                              \
    __builtin_amdgcn_s_setprio(0);                                                 \
    __builtin_amdgcn_s_barrier();                                                  \
  } while (0)

__global__ __launch_bounds__(256, 2) void k_attn(
    const u16* __restrict__ qkv, const u16* __restrict__ vT, u16* __restrict__ o_ws) {
  __shared__ u16 smem[16384];                 // 32 KiB
  u16* const kb0 = smem;
  u16* const kb1 = smem + 4096;
  u16* const vb0 = smem + 8192;
  u16* const vb1 = smem + 12288;

  const int t = threadIdx.x, l = t & 63, w = t >> 6;
  const int lr = l & 15, lk = l >> 4;
  const int f = blockIdx.x;
  const int bg = f & 7;                        // XCD-pinned (b,g)
  const int h = (f >> 3) & 3;
  const int qt = f >> 5;
  const int b = bg >> 2, g = bg & 3;
  const int q0 = qt * 128;
  const int qcol = (g * HPGQ + h) * DH;
  const u16* qbase = qkv + (size_t)(b * SEQ) * NQKV;
  const u16* kbase = qbase + HID + g * DH;
  const u16* vbase = vT + (size_t)(b * GQ + g) * DH * SEQ;

  const int NT = SEQ / 32;
  const int start = (qt * 5 + h * 9) & (NT - 1);

  const int kQ0 = lr * 256 + ((lk ^ (lr & 7) ^ (lr >> 3)) << 4);
  const int vQ0 = lr * 64 + ((lk ^ ((lr >> 1) & 3)) << 4);
  int kOffE[2], vOffE[2];
#pragma unroll
  for (int i = 0; i < 2; ++i) {
    const int e = i * 256 + t;
    const int r = e >> 4, c = e & 15;
    kOffE[i] = r * NQKV + swz(r, c) * 8;
    const int rv = e >> 2, cv = e & 3;
    vOffE[i] = rv * SEQ + ((cv ^ ((rv >> 1) & 3)) * 8);
  }

  bf16x8 qf[2][4];
#pragma unroll
  for (int nq = 0; nq < 2; ++nq)
#pragma unroll
    for (int kk = 0; kk < 4; ++kk)
      qf[nq][kk] = *(const bf16x8*)(qbase + (size_t)(q0 + w * 32 + nq * 16 + lr) * NQKV +
                                    qcol + kk * 32 + lk * 8);

  {
    const int t00 = start * 32;
    const u16* kbT = kbase + (size_t)t00 * NQKV;
    const u16* vbT = vbase + t00;
#pragma unroll
    for (int i = 0; i < 2; ++i) {
      gl16(kbT + kOffE[i], kb0 + (i * 256 + t) * 8);
      gl16(vbT + vOffE[i], vb0 + (i * 256 + t) * 8);
    }
  }

  f32x4 acc_o[2][8] = {};
  f32x4 acc_s[2] = {};

  bf16x8 vones;
#pragma unroll
  for (int j = 0; j < 8; ++j) vones[j] = (lr == 0) ? (__bf16)1.0f : (__bf16)0.0f;

  for (int tp = 0; tp < NT - 2; tp += 2) {
    ATTN_ITER(kb0, vb0, kb1, vb1, tp, true);
    ATTN_ITER(kb1, vb1, kb0, vb0, tp + 1, true);
  }
  ATTN_ITER(kb0, vb0, kb1, vb1, NT - 2, true);
  ATTN_ITER(kb1, vb1, kb0, vb0, NT - 1, false);

#pragma unroll
  for (int nq = 0; nq < 2; ++nq)
#pragma unroll
    for (int r = 0; r < 4; ++r) {
      const float s = __shfl(acc_s[nq][r], l & 48);
      const float inv = 1.0f / s;
      const int q = q0 + w * 32 + nq * 16 + lk * 4 + r;
#pragma unroll
      for (int nd = 0; nd < 8; ++nd) {
        const int d = nd * 16 + lr;
        o_ws[(size_t)(b * SEQ + q) * HID + qcol + d] = f2bf(acc_o[nq][nd][r] * inv);
      }
    }
}

extern "C" void kernel_launch(void* const* d_in, const int* in_sizes, int n_in,
                              void* d_out, int out_size, void* d_ws, size_t ws_size,
                              hipStream_t stream) {
  const float* x  = (const float*)d_in[0];
  const float* Wq = (const float*)d_in[1];
  const float* bq = (const float*)d_in[2];
  const float* Wk = (const float*)d_in[3];
  const float* bk = (const float*)d_in[4];
  const float* Wv = (const float*)d_in[5];
  const float* bv = (const float*)d_in[6];
  const float* Wo = (const float*)d_in[7];
  const float* bo = (const float*)d_in[8];
  float* out = (float*)d_out;

  char* ws = (char*)d_ws;
  u16* x_bf  = (u16*)ws;  ws += (size_t)NTOK * KD * 2;        // 16 MiB (reused as o_ws later)
  u16* qkvT  = (u16*)ws;  ws += (size_t)NQKV * KD * 2;        // 12 MiB
  u16* WoT   = (u16*)ws;  ws += (size_t)HID * KD * 2;         //  8 MiB
  u16* qkv   = (u16*)ws;  ws += (size_t)NTOK * NQKV * 2;      // 24 MiB
  u16* vTb   = (u16*)ws;  ws += (size_t)NBATCH * GQ * DH * SEQ * 2;  // 4 MiB
  u16* o_ws  = x_bf;  // x_bf dead after QKV GEMM; attention output reuses it

  k_prep<<<18432, 256, 0, stream>>>(x, x_bf, Wq, Wk, Wv, Wo, qkvT, WoT);

  k_gemm_qkv<<<dim3(NQKV / 192, NTOK / 256), 512, 0, stream>>>(x_bf, qkvT, qkv, vTb, bq, bk, bv);
  k_attn<<<SEQ / 128 * NBATCH * GQ * HPGQ, 256, 0, stream>>>(qkv, vTb, o_ws);
  k_gemm_o<<<dim3(HID / 128, NTOK / 256), 512, 0, stream>>>(o_ws, WoT, bo, out);
}

// Round 20
// 180.702 us; speedup vs baseline: 1.0017x; 1.0017x over previous
//
#include <hip/hip_runtime.h>

#define HID   2048
#define KD    2048
#define GQ    4
#define HPGQ  4
#define DH    128
#define SEQ   2048
#define NBATCH 2
#define NTOK  (NBATCH * SEQ)   // 4096
#define NQKV  3072

typedef unsigned short u16;
typedef unsigned int   u32;
using bf16x8 = __attribute__((ext_vector_type(8))) __bf16;
using bf16x2 = __attribute__((ext_vector_type(2))) __bf16;
using f32x4  = __attribute__((ext_vector_type(4))) float;
using u32x4  = __attribute__((ext_vector_type(4))) u32;

#if __has_builtin(__builtin_amdgcn_exp2f)
#define FEXP2(x) __builtin_amdgcn_exp2f(x)
#else
#define FEXP2(x) exp2f(x)
#endif

// 1/sqrt(128) * log2(e): folded into Q projection so scores are in log2 domain
#define QSCALE 0.12751744f

__device__ __forceinline__ u16 f2bf(float f) {
  union { float f; u32 u; } v; v.f = f;
  u32 u = v.u + 0x7fffu + ((v.u >> 16) & 1u);
  return (u16)(u >> 16);
}

__device__ __forceinline__ u32 pk2(float a, float b) {
  bf16x2 t;
  t[0] = (__bf16)a;
  t[1] = (__bf16)b;
  return __builtin_bit_cast(u32, t);
}

__device__ __forceinline__ void gl16(const void* g, void* l) {
  __builtin_amdgcn_global_load_lds((const __attribute__((address_space(1))) u32*)g,
                                   (__attribute__((address_space(3))) u32*)l, 16, 0, 0);
}

// staging-side swizzle (only used OUTSIDE hot loops, for lane-invariant offsets)
__device__ __forceinline__ int swz(int r, int c) {
  return (c & ~7) | ((c ^ r ^ (r >> 3)) & 7);
}

// ---------------- fused prep: fp32->bf16 convert of x + all weight transposes ----
__global__ __launch_bounds__(256) void k_prep(
    const float* __restrict__ x, u16* __restrict__ x_bf,
    const float* __restrict__ Wq, const float* __restrict__ Wk,
    const float* __restrict__ Wv, const float* __restrict__ Wo,
    u16* __restrict__ qkvT, u16* __restrict__ WoT) {
  __shared__ float tile[32][33];
  const int bid = blockIdx.x;
  if (bid < 8192) {
    const int i = bid * 256 + threadIdx.x;
    const float4 v = ((const float4*)x)[i];
    ushort4 o;
    o.x = f2bf(v.x); o.y = f2bf(v.y); o.z = f2bf(v.z); o.w = f2bf(v.w);
    ((ushort4*)x_bf)[i] = o;
    return;
  }
  int idx = bid - 8192;
  const float* W; u16* WT; int N, rowoff, bx, by;
  if (idx < 4096)      {             W = Wq; WT = qkvT; N = 2048; rowoff = 0;    bx = idx & 63; by = idx >> 6; }
  else if (idx < 5120) { idx -= 4096; W = Wk; WT = qkvT; N = 512;  rowoff = 2048; bx = idx & 15; by = idx >> 4; }
  else if (idx < 6144) { idx -= 5120; W = Wv; WT = qkvT; N = 512;  rowoff = 2560; bx = idx & 15; by = idx >> 4; }
  else                 { idx -= 6144; W = Wo; WT = WoT;  N = 2048; rowoff = 0;    bx = idx & 63; by = idx >> 6; }
  const int tx = threadIdx.x & 31, ty = threadIdx.x >> 5;
  const int k0 = by * 32, n0 = bx * 32;
#pragma unroll
  for (int i = 0; i < 4; ++i)
    tile[ty + 8 * i][tx] = W[(size_t)(k0 + ty + 8 * i) * N + (n0 + tx)];
  __syncthreads();
#pragma unroll
  for (int i = 0; i < 4; ++i)
    WT[(size_t)(rowoff + n0 + ty + 8 * i) * KD + (k0 + tx)] = f2bf(tile[tx][ty + 8 * i]);
}

// ================= 256x192 8-wave pipelined GEMM (QKV) ========================
#define BUFB 57344

#define STG128(OP, ROWB, KTB, LBYTE)                                               \
  { _Pragma("unroll") for (int i = 0; i < 2; ++i)                                  \
      gl16((OP) + (size_t)(ROWB) * KD + (KTB) + stOffE[i],                         \
           (u16*)((char*)S + (LBYTE)) + (i * 512 + t) * 8); }
#define STG64(OP, ROWB, KTB, LBYTE)                                                \
  gl16((OP) + (size_t)(ROWB) * KD + (KTB) + stOffE[0],                             \
       (u16*)((char*)S + (LBYTE)) + t * 8);

#define STAGE_B(D, KTB)                                                            \
  STG128(Bt, n0b,       (KTB), (D) * BUFB + 32768);                                \
  STG64 (Bt, n0b + 128, (KTB), (D) * BUFB + 49152);
#define STAGE_A(D, KTB)                                                            \
  STG128(A,  m0,        (KTB), (D) * BUFB + 0);                                    \
  STG128(A,  m0 + 128,  (KTB), (D) * BUFB + 16384);

#define RDA(D, M, KC) (*(const bf16x8*)((const char*)S + (D) * BUFB + (M) * 2048 + (aQ ^ ((KC) << 6))))
#define RDB(D, NT, KC) (*(const bf16x8*)((const char*)S + (D) * BUFB + (NT) * 2048 + (bQ ^ ((KC) << 6))))

#define MFMA8(MB, NT)                                                              \
  _Pragma("unroll") for (int m = 0; m < 4; ++m)                                    \
    _Pragma("unroll") for (int kc = 0; kc < 2; ++kc)                               \
      acc[(MB) + m][NT] = __builtin_amdgcn_mfma_f32_16x16x32_bf16(                 \
          afr[m][kc], bfr[NT][kc], acc[(MB) + m][NT], 0, 0, 0);

#define ITERQ(D, KTN, PRE)                                                         \
  do {                                                                             \
    _Pragma("unroll") for (int m = 0; m < 4; ++m)                                  \
      _Pragma("unroll") for (int kc = 0; kc < 2; ++kc)                             \
        afr[m][kc] = RDA(D, m, kc);                                                \
    _Pragma("unroll") for (int nt = 0; nt < 3; ++nt)                               \
      _Pragma("unroll") for (int kc = 0; kc < 2; ++kc)                             \
        bfr[nt][kc] = RDB(D, nt, kc);                                              \
    __builtin_amdgcn_s_setprio(1);                                                 \
    MFMA8(0, 0) MFMA8(0, 1) MFMA8(0, 2)                                            \
    __builtin_amdgcn_s_setprio(0);                                                 \
    _Pragma("unroll") for (int m = 0; m < 4; ++m)                                  \
      _Pragma("unroll") for (int kc = 0; kc < 2; ++kc)                             \
        afr[m][kc] = RDA(D, 4 + m, kc);                                            \
    asm volatile("s_waitcnt lgkmcnt(0)" ::: "memory");                             \
    __builtin_amdgcn_s_barrier();                                                  \
    if (PRE) {                                                                     \
      STAGE_B(D, KTN);                                                             \
      STAGE_A(D, KTN);                                                             \
      asm volatile("s_waitcnt vmcnt(7)" ::: "memory");                             \
    } else {                                                                       \
      asm volatile("s_waitcnt vmcnt(0)" ::: "memory");                             \
    }                                                                              \
    __builtin_amdgcn_s_barrier();                                                  \
    __builtin_amdgcn_s_setprio(1);                                                 \
    MFMA8(4, 0) MFMA8(4, 1) MFMA8(4, 2)                                            \
    __builtin_amdgcn_s_setprio(0);                                                 \
  } while (0)

__global__ __launch_bounds__(512, 1) void k_gemm_qkv(
    const u16* __restrict__ A, const u16* __restrict__ Bt,
    u16* __restrict__ qkv, u16* __restrict__ vT,
    const float* __restrict__ bq, const float* __restrict__ bk,
    const float* __restrict__ bv) {
  __shared__ u16 S[BUFB];                     // 112 KiB
  const int t = threadIdx.x, l = t & 63, w = t >> 6;
  const int lr = l & 15, lk = l >> 4;
  const int wm = w >> 2, wn = w & 3;
  const int m0 = blockIdx.y * 256, n0b = blockIdx.x * 192;

  int stOffE[2];
#pragma unroll
  for (int i = 0; i < 2; ++i) {
    const int e = i * 512 + t;
    const int r = e >> 3;
    stOffE[i] = r * KD + ((e & 7) ^ (r & 7)) * 8;
  }
  const int qb = lr * 128 + (((lr >> 2) & 1) << 6) + ((lk ^ (lr & 3)) << 4);
  const int aQ = wm * 16384 + qb;
  const int bQ = 32768 + wn * 6144 + qb;

  f32x4 acc[8][3] = {};
  bf16x8 afr[4][2], bfr[3][2];

  STAGE_A(0, 0);  STAGE_B(0, 0);
  STAGE_A(1, 64); STAGE_B(1, 64);
  asm volatile("s_waitcnt vmcnt(7)" ::: "memory");
  __builtin_amdgcn_s_barrier();

  for (int j = 0; j < 30; j += 2) {
    ITERQ(0, (j + 2) * 64, true);
    ITERQ(1, (j + 3) * 64, true);
  }
  ITERQ(0, 0, false);
  ITERQ(1, 0, false);

  const int gmB = m0 + wm * 128, gnB = n0b + wn * 48;
#pragma unroll
  for (int m = 0; m < 8; ++m) {
    const int row0 = gmB + m * 16 + lk * 4;
#pragma unroll
    for (int nt = 0; nt < 3; ++nt) {
      const int col = gnB + nt * 16 + lr;
      float bias, qs = 1.0f;
      if (col < HID) { bias = bq[col]; qs = QSCALE; }
      else if (col < HID + 512) bias = bk[col - HID];
      else bias = bv[col - HID - 512];
      if (col < HID + 512) {
#pragma unroll
        for (int r = 0; r < 4; ++r)
          qkv[(size_t)(row0 + r) * NQKV + col] = f2bf((acc[m][nt][r] + bias) * qs);
      } else {
        const int gg = (col - 2560) >> 7, d = (col - 2560) & 127;
        const int b = row0 >> 11, s0 = row0 & 2047;
        ushort4 pk;
        pk.x = f2bf(acc[m][nt][0] + bias);
        pk.y = f2bf(acc[m][nt][1] + bias);
        pk.z = f2bf(acc[m][nt][2] + bias);
        pk.w = f2bf(acc[m][nt][3] + bias);
        *(ushort4*)(vT + ((size_t)(b * GQ + gg) * DH + d) * SEQ + s0) = pk;
      }
    }
  }
}

// ================= 256x128 8-wave pipelined GEMM (O projection) =================
#define OBUFB 49152

#define OSTAGE_B(D, KTB)                                                           \
  STG128(Bt, n0b, (KTB), (D) * OBUFB + 32768);
#define OSTAGE_A(D, KTB)                                                           \
  STG128(A,  m0,       (KTB), (D) * OBUFB + 0);                                    \
  STG128(A,  m0 + 128, (KTB), (D) * OBUFB + 16384);

#define ORDA(D, M, KC) (*(const bf16x8*)((const char*)S + (D) * OBUFB + (M) * 2048 + (aQ ^ ((KC) << 6))))
#define ORDB(D, NT, KC) (*(const bf16x8*)((const char*)S + (D) * OBUFB + (NT) * 2048 + (bQ ^ ((KC) << 6))))

#define OMFMA8(MB, NT)                                                             \
  _Pragma("unroll") for (int m = 0; m < 4; ++m)                                    \
    _Pragma("unroll") for (int kc = 0; kc < 2; ++kc)                               \
      acc[(MB) + m][NT] = __builtin_amdgcn_mfma_f32_16x16x32_bf16(                 \
          afr[m][kc], bfr[NT][kc], acc[(MB) + m][NT], 0, 0, 0);

#define ITERO(D, KTN, PRE)                                                         \
  do {                                                                             \
    _Pragma("unroll") for (int m = 0; m < 4; ++m)                                  \
      _Pragma("unroll") for (int kc = 0; kc < 2; ++kc)                             \
        afr[m][kc] = ORDA(D, m, kc);                                               \
    _Pragma("unroll") for (int nt = 0; nt < 2; ++nt)                               \
      _Pragma("unroll") for (int kc = 0; kc < 2; ++kc)                             \
        bfr[nt][kc] = ORDB(D, nt, kc);                                             \
    __builtin_amdgcn_s_setprio(1);                                                 \
    OMFMA8(0, 0) OMFMA8(0, 1)                                                      \
    __builtin_amdgcn_s_setprio(0);                                                 \
    _Pragma("unroll") for (int m = 0; m < 4; ++m)                                  \
      _Pragma("unroll") for (int kc = 0; kc < 2; ++kc)                             \
        afr[m][kc] = ORDA(D, 4 + m, kc);                                           \
    asm volatile("s_waitcnt lgkmcnt(0)" ::: "memory");                             \
    __builtin_amdgcn_s_barrier();                                                  \
    if (PRE) {                                                                     \
      OSTAGE_B(D, KTN);                                                            \
      OSTAGE_A(D, KTN);                                                            \
      asm volatile("s_waitcnt vmcnt(6)" ::: "memory");                             \
    } else {                                                                       \
      asm volatile("s_waitcnt vmcnt(0)" ::: "memory");                             \
    }                                                                              \
    __builtin_amdgcn_s_barrier();                                                  \
    __builtin_amdgcn_s_setprio(1);                                                 \
    OMFMA8(4, 0) OMFMA8(4, 1)                                                      \
    __builtin_amdgcn_s_setprio(0);                                                 \
  } while (0)

__global__ __launch_bounds__(512, 1) void k_gemm_o(
    const u16* __restrict__ A, const u16* __restrict__ Bt,
    const float* __restrict__ bo, float* __restrict__ C) {
  __shared__ u16 S[OBUFB];                    // 96 KiB
  const int t = threadIdx.x, l = t & 63, w = t >> 6;
  const int lr = l & 15, lk = l >> 4;
  const int wm = w >> 2, wn = w & 3;
  const int m0 = blockIdx.y * 256, n0b = blockIdx.x * 128;

  int stOffE[2];
#pragma unroll
  for (int i = 0; i < 2; ++i) {
    const int e = i * 512 + t;
    const int r = e >> 3;
    stOffE[i] = r * KD + ((e & 7) ^ (r & 7)) * 8;
  }
  const int qb = lr * 128 + (((lr >> 2) & 1) << 6) + ((lk ^ (lr & 3)) << 4);
  const int aQ = wm * 16384 + qb;
  const int bQ = 32768 + wn * 4096 + qb;

  f32x4 acc[8][2] = {};
  bf16x8 afr[4][2], bfr[2][2];

  OSTAGE_A(0, 0);  OSTAGE_B(0, 0);
  OSTAGE_A(1, 64); OSTAGE_B(1, 64);
  asm volatile("s_waitcnt vmcnt(6)" ::: "memory");
  __builtin_amdgcn_s_barrier();

  for (int j = 0; j < 30; j += 2) {
    ITERO(0, (j + 2) * 64, true);
    ITERO(1, (j + 3) * 64, true);
  }
  ITERO(0, 0, false);
  ITERO(1, 0, false);

  const int gmB = m0 + wm * 128, gnB = n0b + wn * 32;
#pragma unroll
  for (int m = 0; m < 8; ++m) {
    const int row0 = gmB + m * 16 + lk * 4;
#pragma unroll
    for (int nt = 0; nt < 2; ++nt) {
      const int col = gnB + nt * 16 + lr;
      const float bias = bo[col];
#pragma unroll
      for (int r = 0; r < 4; ++r)
        C[(size_t)(row0 + r) * HID + col] = acc[m][nt][r] + bias;
    }
  }
}

// ================= Flash attention (round-12 proven version: QBLK=128, KVBLK=32) ==
#define ATTN_ITER(KS, VS, KN, VN, TTV, PRE)                                        \
  do {                                                                             \
    if (PRE) {                                                                     \
      const int t0n = ((start + (TTV) + 1) & (NT - 1)) * 32;                       \
      const u16* kbT = kbase + (size_t)t0n * NQKV;                                 \
      const u16* vbT = vbase + t0n;                                                \
      _Pragma("unroll")                                                            \
      for (int i = 0; i < 2; ++i) {                                                \
        gl16(kbT + kOffE[i], (KN) + (i * 256 + t) * 8);                            \
        gl16(vbT + vOffE[i], (VN) + (i * 256 + t) * 8);                            \
      }                                                                            \
      asm volatile("s_waitcnt vmcnt(4)" ::: "memory");                             \
    } else {                                                                       \
      asm volatile("s_waitcnt vmcnt(0)" ::: "memory");                             \
    }                                                                              \
    __builtin_amdgcn_s_barrier();                                                  \
    f32x4 sc[2][2] = {};                                                           \
    __builtin_amdgcn_s_setprio(1);                                                 \
    _Pragma("unroll")                                                              \
    for (int kk = 0; kk < 4; ++kk) {                                               \
      bf16x8 kf[2];                                                                \
      _Pragma("unroll")                                                            \
      for (int mk = 0; mk < 2; ++mk) {                                             \
        const int LIT = (mk << 12) ^ ((kk >> 1) << 7) ^ ((kk & 1) << 6) ^ (mk << 5); \
        kf[mk] = *(const bf16x8*)((const char*)(KS) + (kQ0 ^ LIT));                \
      }                                                                            \
      _Pragma("unroll")                                                            \
      for (int nq = 0; nq < 2; ++nq)                                               \
        _Pragma("unroll")                                                          \
        for (int mk = 0; mk < 2; ++mk)                                             \
          sc[nq][mk] = __builtin_amdgcn_mfma_f32_16x16x32_bf16(kf[mk], qf[nq][kk], sc[nq][mk], 0, 0, 0); \
    }                                                                              \
    __builtin_amdgcn_s_setprio(0);                                                 \
    bf16x8 pa[2];                                                                  \
    _Pragma("unroll")                                                              \
    for (int nq = 0; nq < 2; ++nq) {                                               \
      u32 w0 = pk2(FEXP2(sc[nq][0][0]), FEXP2(sc[nq][0][1]));                      \
      u32 w1 = pk2(FEXP2(sc[nq][0][2]), FEXP2(sc[nq][0][3]));                      \
      u32 w2 = pk2(FEXP2(sc[nq][1][0]), FEXP2(sc[nq][1][1]));                      \
      u32 w3 = pk2(FEXP2(sc[nq][1][2]), FEXP2(sc[nq][1][3]));                      \
      asm("v_permlane32_swap_b32 %0, %1" : "+v"(w0), "+v"(w2));                    \
      asm("v_permlane32_swap_b32 %0, %1" : "+v"(w1), "+v"(w3));                    \
      asm("v_permlane16_swap_b32 %0, %1" : "+v"(w0), "+v"(w2));                    \
      asm("v_permlane16_swap_b32 %0, %1" : "+v"(w1), "+v"(w3));                    \
      u32x4 u = {w0, w1, w2, w3};                                                  \
      pa[nq] = __builtin_bit_cast(bf16x8, u);                                      \
    }                                                                              \
    __builtin_amdgcn_s_setprio(1);                                                 \
    _Pragma("unroll")                                                              \
    for (int nq = 0; nq < 2; ++nq)                                                 \
      acc_s[nq] = __builtin_amdgcn_mfma_f32_16x16x32_bf16(pa[nq], vones, acc_s[nq], 0, 0, 0); \
    _Pragma("unroll")                                                              \
    for (int nd = 0; nd < 8; ++nd) {                                               \
      const bf16x8 vf = *(const bf16x8*)((const char*)(VS) + vQ0 + nd * 1024);     \
      _Pragma("unroll")                                                            \
      for (int nq = 0; nq < 2; ++nq)                                               \
        acc_o[nq][nd] = __builtin_amdgcn_mfma_f32_16x16x32_bf16(pa[nq], vf, acc_o[nq][nd], 0, 0, 0); \
    }                                                                              \
    __builtin_amdgcn_s_setprio(0);                                                 \
    __builtin_amdgcn_s_barrier();                                                  \
  } while (0)

__global__ __launch_bounds__(256, 2) void k_attn(
    const u16* __restrict__ qkv, const u16* __restrict__ vT, u16* __restrict__ o_ws) {
  __shared__ u16 smem[16384];                 // 32 KiB
  u16* const kb0 = smem;
  u16* const kb1 = smem + 4096;
  u16* const vb0 = smem + 8192;
  u16* const vb1 = smem + 12288;

  const int t = threadIdx.x, l = t & 63, w = t >> 6;
  const int lr = l & 15, lk = l >> 4;
  const int f = blockIdx.x;
  const int bg = f & 7;                        // XCD-pinned (b,g)
  const int h = (f >> 3) & 3;
  const int qt = f >> 5;
  const int b = bg >> 2, g = bg & 3;
  const int q0 = qt * 128;
  const int qcol = (g * HPGQ + h) * DH;
  const u16* qbase = qkv + (size_t)(b * SEQ) * NQKV;
  const u16* kbase = qbase + HID + g * DH;
  const u16* vbase = vT + (size_t)(b * GQ + g) * DH * SEQ;

  const int NT = SEQ / 32;
  const int start = (qt * 5 + h * 9) & (NT - 1);

  const int kQ0 = lr * 256 + ((lk ^ (lr & 7) ^ (lr >> 3)) << 4);
  const int vQ0 = lr * 64 + ((lk ^ ((lr >> 1) & 3)) << 4);
  int kOffE[2], vOffE[2];
#pragma unroll
  for (int i = 0; i < 2; ++i) {
    const int e = i * 256 + t;
    const int r = e >> 4, c = e & 15;
    kOffE[i] = r * NQKV + swz(r, c) * 8;
    const int rv = e >> 2, cv = e & 3;
    vOffE[i] = rv * SEQ + ((cv ^ ((rv >> 1) & 3)) * 8);
  }

  bf16x8 qf[2][4];
#pragma unroll
  for (int nq = 0; nq < 2; ++nq)
#pragma unroll
    for (int kk = 0; kk < 4; ++kk)
      qf[nq][kk] = *(const bf16x8*)(qbase + (size_t)(q0 + w * 32 + nq * 16 + lr) * NQKV +
                                    qcol + kk * 32 + lk * 8);

  {
    const int t00 = start * 32;
    const u16* kbT = kbase + (size_t)t00 * NQKV;
    const u16* vbT = vbase + t00;
#pragma unroll
    for (int i = 0; i < 2; ++i) {
      gl16(kbT + kOffE[i], kb0 + (i * 256 + t) * 8);
      gl16(vbT + vOffE[i], vb0 + (i * 256 + t) * 8);
    }
  }

  f32x4 acc_o[2][8] = {};
  f32x4 acc_s[2] = {};

  bf16x8 vones;
#pragma unroll
  for (int j = 0; j < 8; ++j) vones[j] = (lr == 0) ? (__bf16)1.0f : (__bf16)0.0f;

  for (int tp = 0; tp < NT - 2; tp += 2) {
    ATTN_ITER(kb0, vb0, kb1, vb1, tp, true);
    ATTN_ITER(kb1, vb1, kb0, vb0, tp + 1, true);
  }
  ATTN_ITER(kb0, vb0, kb1, vb1, NT - 2, true);
  ATTN_ITER(kb1, vb1, kb0, vb0, NT - 1, false);

#pragma unroll
  for (int nq = 0; nq < 2; ++nq)
#pragma unroll
    for (int r = 0; r < 4; ++r) {
      const float s = __shfl(acc_s[nq][r], l & 48);
      const float inv = 1.0f / s;
      const int q = q0 + w * 32 + nq * 16 + lk * 4 + r;
#pragma unroll
      for (int nd = 0; nd < 8; ++nd) {
        const int d = nd * 16 + lr;
        o_ws[(size_t)(b * SEQ + q) * HID + qcol + d] = f2bf(acc_o[nq][nd][r] * inv);
      }
    }
}

extern "C" void kernel_launch(void* const* d_in, const int* in_sizes, int n_in,
                              void* d_out, int out_size, void* d_ws, size_t ws_size,
                              hipStream_t stream) {
  const float* x  = (const float*)d_in[0];
  const float* Wq = (const float*)d_in[1];
  const float* bq = (const float*)d_in[2];
  const float* Wk = (const float*)d_in[3];
  const float* bk = (const float*)d_in[4];
  const float* Wv = (const float*)d_in[5];
  const float* bv = (const float*)d_in[6];
  const float* Wo = (const float*)d_in[7];
  const float* bo = (const float*)d_in[8];
  float* out = (float*)d_out;

  char* ws = (char*)d_ws;
  u16* x_bf  = (u16*)ws;  ws += (size_t)NTOK * KD * 2;        // 16 MiB (reused as o_ws later)
  u16* qkvT  = (u16*)ws;  ws += (size_t)NQKV * KD * 2;        // 12 MiB
  u16* WoT   = (u16*)ws;  ws += (size_t)HID * KD * 2;         //  8 MiB
  u16* qkv   = (u16*)ws;  ws += (size_t)NTOK * NQKV * 2;      // 24 MiB
  u16* vTb   = (u16*)ws;  ws += (size_t)NBATCH * GQ * DH * SEQ * 2;  // 4 MiB
  u16* o_ws  = x_bf;  // x_bf dead after QKV GEMM; attention output reuses it

  k_prep<<<18432, 256, 0, stream>>>(x, x_bf, Wq, Wk, Wv, Wo, qkvT, WoT);

  k_gemm_qkv<<<dim3(NQKV / 192, NTOK / 256), 512, 0, stream>>>(x_bf, qkvT, qkv, vTb, bq, bk, bv);
  k_attn<<<SEQ / 128 * NBATCH * GQ * HPGQ, 256, 0, stream>>>(qkv, vTb, o_ws);
  k_gemm_o<<<dim3(HID / 128, NTOK / 256), 512, 0, stream>>>(o_ws, WoT, bo, out);
}